// Round 11
// baseline (77.387 us; speedup 1.0000x reference)
//
#include <hip/hip_runtime.h>

#define THREADS 512
#define RB      128      // rows per mainK block
#define RB2     64       // rows per finK block
#define SCAP    64       // slot capacity (tau targets T~32: huge headroom, P(T>64)~3e-7 -> ovf path)
#define KF      80       // compiled K (harness K=80)
#define K2      160      // 2*KF (C|D)

typedef float f4 __attribute__((ext_vector_type(4)));

__device__ __forceinline__ unsigned fmap(float x) {   // order-preserving float->uint
  unsigned u = __float_as_uint(x);
  return (u >> 31) ? ~u : (u | 0x80000000u);
}

// ============ mainK: list + assign + LDS slot table + DENSE record dump (plain stores, no init) ============
__global__ __launch_bounds__(THREADS)
void mainK(const float* __restrict__ S, const float* __restrict__ J,
           const float* __restrict__ C, const float* __restrict__ D,
           float tau,
           float* __restrict__ recSum, int* __restrict__ recCnt,
           int* __restrict__ leader, int* __restrict__ lslot,
           int N, int K) {
  __shared__ int   listIdx[SCAP];
  __shared__ float listVal[SCAP];
  __shared__ int   wsum[8], wpre[8];
  __shared__ unsigned long long rowKey[RB];
  __shared__ int   rowSlot[RB];
  __shared__ float slotSum[SCAP * K2];   // 40 KB, dense slot-indexed
  __shared__ int   slotCnt[SCAP];
  __shared__ int   sT;
  __shared__ unsigned long long bkey;

  const int tid = threadIdx.x, lane = tid & 63, wv = tid >> 6;
  const int b = blockIdx.x, i0 = b * RB;

  // ---- A: block-invariant candidate list {j : S[j] >= tau}, index-ascending ----
  int T;
  {
    const bool vec4 = ((N & 3) == 0);
    int cl = 0;
    int a0 = 0, a1 = 0, j0 = 0, j1 = 0;
    if (vec4) {
      const int n4 = N >> 2;
      const int per4 = (n4 + THREADS - 1) / THREADS;
      a0 = tid * per4; a1 = min(n4, a0 + per4);
      for (int a = a0; a < a1; ++a) {
        f4 v = ((const f4*)S)[a];
        cl += (v.x >= tau) + (v.y >= tau) + (v.z >= tau) + (v.w >= tau);
      }
    } else {
      const int per = (N + THREADS - 1) / THREADS;
      j0 = tid * per; j1 = min(N, j0 + per);
      for (int j = j0; j < j1; ++j) cl += (S[j] >= tau);
    }
    int inc = cl;                          // two-level exclusive prefix over 512 counts
    for (int off = 1; off < 64; off <<= 1) {
      int o = __shfl_up(inc, off, 64);
      if (lane >= off) inc += o;
    }
    if (lane == 63) wsum[wv] = inc;
    __syncthreads();
    if (tid == 0) {
      int acc = 0;
      #pragma unroll
      for (int w = 0; w < 8; ++w) { wpre[w] = acc; acc += wsum[w]; }
      sT = acc;
    }
    __syncthreads();
    T = sT;
    if (T <= SCAP) {
      int pos = wpre[wv] + inc - cl;
      if (vec4) {
        for (int a = a0; a < a1; ++a) {
          f4 v = ((const f4*)S)[a];
          if (v.x >= tau) { listIdx[pos] = a*4+0; listVal[pos] = v.x; ++pos; }
          if (v.y >= tau) { listIdx[pos] = a*4+1; listVal[pos] = v.y; ++pos; }
          if (v.z >= tau) { listIdx[pos] = a*4+2; listVal[pos] = v.z; ++pos; }
          if (v.w >= tau) { listIdx[pos] = a*4+3; listVal[pos] = v.w; ++pos; }
        }
      } else {
        for (int j = j0; j < j1; ++j) {
          float v = S[j];
          if (v >= tau) { listIdx[pos] = j; listVal[pos] = v; ++pos; }
        }
      }
    }
  }
  const int ovf = (T > SCAP) | (K != KF);  // unconditional-correctness escape hatch

  // zero LDS slot table + row state (always: dumped dense at the end)
  for (int idx = tid; idx < SCAP * K2; idx += THREADS) slotSum[idx] = 0.f;
  if (tid < SCAP) slotCnt[tid] = 0;
  if (tid < RB) { rowKey[tid] = 0ull; rowSlot[tid] = -1; }
  __syncthreads();

  // ---- B: leader assign, 4 threads/row over list slots; exact when a top-set nbr exists ----
  {
    const int r = tid & (RB - 1);          // 0..127 row
    const int g = tid >> 7;                // 0..3 candidate group
    const int i = i0 + r;
    if (!ovf && i < N) {
      unsigned long long lk = 0ull;
      for (int t = g; t < T; t += 4) {
        const int cand = listIdx[t];
        float v = J[(size_t)cand * N + i];   // symmetric J: coalesced column read (diag=1 covers self)
        if (v > 0.5f || cand == i) {
          unsigned long long key = ((unsigned long long)fmap(listVal[t]) << 32)
                                 | (unsigned)(0xFFFFFFFFu - (unsigned)t);
          if (key > lk) lk = key;            // index-ascending slots: min slot == min index
        }
      }
      if (lk) atomicMax(&rowKey[r], lk);
    }
  }
  __syncthreads();
  if (tid < RB) {
    const int i = i0 + tid;
    if (i < N) {
      unsigned long long kk = ovf ? 0ull : rowKey[tid];
      if (kk != 0ull) {
        int slot = (int)(0xFFFFFFFFu - (unsigned)(kk & 0xFFFFFFFFull));
        rowSlot[tid] = slot;
        leader[i] = listIdx[slot];           // plain stores: kernel boundary syncs
        lslot[i]  = slot;
        atomicAdd(&slotCnt[slot], 1);
      } else {
        lslot[i] = -1;                       // brute below fills leader
      }
    }
  }
  __syncthreads();

  // ---- B': exact full-row argmax for unresolved rows (expected: none) ----
  for (int rr = 0; rr < RB; ++rr) {
    if (rowSlot[rr] != -1) continue;         // uniform branch (LDS)
    const int ii = i0 + rr;
    if (ii >= N) continue;
    if (tid == 0) bkey = 0ull;
    __syncthreads();
    unsigned long long bk = 0ull;
    for (int j = tid; j < N; j += THREADS) {
      float v = J[(size_t)ii * N + j];
      if (v > 0.5f || j == ii) {
        unsigned long long key = ((unsigned long long)fmap(S[j]) << 32)
                               | (unsigned)(0xFFFFFFFFu - (unsigned)j);
        if (key > bk) bk = key;
      }
    }
    if (bk) atomicMax(&bkey, bk);
    __syncthreads();
    if (tid == 0) leader[ii] = (int)(0xFFFFFFFFu - (unsigned)(bkey & 0xFFFFFFFFull));
    __syncthreads();
  }

  // ---- C: accumulate own rows into dense LDS slot table ----
  for (int q = tid; q < RB * 40; q += THREADS) {      // 40 f4 per row (C:20|D:20)
    const int rr = q / 40, f = q - rr * 40;
    const int i = i0 + rr;
    if (i >= N) continue;
    const int s = rowSlot[rr];
    if (s < 0) continue;
    f4 v;
    if (f < 20) v = *(const f4*)(C + (size_t)i * KF + f * 4);
    else        v = *(const f4*)(D + (size_t)i * KF + (f - 20) * 4);
    float* dst = &slotSum[s * K2 + (f < 20 ? f * 4 : KF + (f - 20) * 4)];
    atomicAdd(dst + 0, v.x); atomicAdd(dst + 1, v.y);
    atomicAdd(dst + 2, v.z); atomicAdd(dst + 3, v.w);
  }
  __syncthreads();

  // ---- D: DENSE dump of the whole table -> record b (plain f4/int stores; zero slots included) ----
  {
    f4* dst = (f4*)recSum + (size_t)b * SCAP * 40;
    const f4* src = (const f4*)slotSum;
    for (int q = tid; q < SCAP * 40; q += THREADS) dst[q] = src[q];
    if (tid < SCAP) recCnt[b * SCAP + tid] = slotCnt[tid];
  }
}

// ============ finK: parallel dense gather of global sums + row writes ============
__global__ __launch_bounds__(THREADS)
void finK(const float* __restrict__ recSum, const int* __restrict__ recCnt,
          const int* __restrict__ leader, const int* __restrict__ lslot,
          const float* __restrict__ C, const float* __restrict__ D,
          float* __restrict__ out, int N, int K, int nbm) {
  __shared__ float accS[SCAP * K2];   // 40 KB (worst case all 64 slots touched)
  __shared__ int   rslot[RB2];
  __shared__ int   sMap[SCAP];        // slot -> loc (-1 if untouched)
  __shared__ int   tslot[SCAP];       // loc -> slot
  __shared__ float invS[SCAP];
  __shared__ int   sNT2;
  const int tid = threadIdx.x;
  const int g = blockIdx.x, r0 = g * RB2;
  const size_t NK = (size_t)N * K;

  if (tid < SCAP) sMap[tid] = -1;
  if (tid < RB2) {
    const int i = r0 + tid;
    rslot[tid] = (i < N) ? lslot[i] : -3;
  }
  __syncthreads();
  if (tid < RB2) {
    const int s = rslot[tid];
    if (s >= 0) sMap[s] = 1;          // benign race: flag only
  }
  __syncthreads();
  if (tid < SCAP) {                   // SCAP==64: exactly wave 0 -> full-wave ballot
    const bool flag = (sMap[tid] == 1);
    unsigned long long m = __ballot(flag);
    const int loc = (int)__popcll(m & ((1ull << tid) - 1ull));
    if (flag) { tslot[loc] = tid; sMap[tid] = loc; } else sMap[tid] = -1;
    if (tid == 0) sNT2 = (int)__popcll(m);
  }
  __syncthreads();
  const int nT2 = sNT2;

  // counts: one thread per touched slot, independent scalar loads over records
  if (tid < nT2) {
    const int s = tslot[tid];
    int c = 0;
    for (int b2 = 0; b2 < nbm; ++b2) c += recCnt[b2 * SCAP + s];
    invS[tid] = 1.0f / (float)(c > 0 ? c : 1);
  }

  // sums: thread (loc, f4) register-accumulates over records — independent coalesced f4 loads
  for (int q = tid; q < nT2 * 40; q += THREADS) {
    const int loc = q / 40, f = q - loc * 40;
    const int s = tslot[loc];
    const f4* base = (const f4*)recSum + (size_t)s * 40 + f;
    f4 a = { 0.f, 0.f, 0.f, 0.f };
    for (int b2 = 0; b2 < nbm; ++b2)
      a += base[(size_t)b2 * SCAP * 40];
    *(f4*)&accS[loc * K2 + f * 4] = a;
  }
  __syncthreads();

  // write resolved rows (coalesced f4)
  for (int q = tid; q < RB2 * 40; q += THREADS) {
    const int rr = q / 40, f = q - rr * 40;
    const int i = r0 + rr;
    if (i >= N) continue;
    const int s = rslot[rr];
    if (s < 0) continue;
    const int loc = sMap[s];
    const float iv = invS[loc];
    const f4 v0 = *(const f4*)&accS[loc * K2 + (f < 20 ? f * 4 : KF + (f - 20) * 4)];
    f4 v = { v0.x * iv, v0.y * iv, v0.z * iv, v0.w * iv };
    const size_t off = (f < 20) ? ((size_t)i * KF + f * 4)
                                : (NK + (size_t)i * KF + (f - 20) * 4);
    *(f4*)(out + off) = v;
  }

  // fallback rows: exact leader-scan mean (expected: none; any K)
  for (int rr = 0; rr < RB2; ++rr) {
    if (rslot[rr] != -1) continue;
    const int ii = r0 + rr;
    const int m = leader[ii];
    for (int k = tid; k < K; k += THREADS) {
      float sc = 0.f, sd = 0.f; int cc = 0;
      for (int y = 0; y < N; ++y)
        if (leader[y] == m) { sc += C[(size_t)y * K + k]; sd += D[(size_t)y * K + k]; ++cc; }
      const float iv = 1.0f / (float)(cc > 0 ? cc : 1);
      out[(size_t)ii * K + k] = sc * iv;
      out[NK + (size_t)ii * K + k] = sd * iv;
    }
  }
}

extern "C" void kernel_launch(void* const* d_in, const int* in_sizes, int n_in,
                              void* d_out, int out_size, void* d_ws, size_t ws_size,
                              hipStream_t stream) {
  (void)n_in; (void)out_size; (void)ws_size;
  const float* S = (const float*)d_in[0];
  const float* J = (const float*)d_in[1];
  const float* C = (const float*)d_in[2];
  const float* D = (const float*)d_in[3];
  float* out = (float*)d_out;
  const int N = in_sizes[0];
  const int K = in_sizes[2] / N;
  const int nbm = (N + RB - 1) / RB;       // 64 mainK blocks for N=8192

  // ws layout (NO init — every byte read is written this call):
  // recSum[nbm][SCAP][K2] | recCnt[nbm][SCAP] | leader[N] | lslot[N]
  float* recSum = (float*)d_ws;
  int*   recCnt = (int*)(recSum + (size_t)nbm * SCAP * K2);
  int*   leader = recCnt + (size_t)nbm * SCAP;
  int*   lslot  = leader + N;

  const float tau = 1.0f - 32.0f / (float)N;   // targets E[T]=32; any tau is correct
  mainK<<<nbm, THREADS, 0, stream>>>(S, J, C, D, tau, recSum, recCnt, leader, lslot, N, K);
  const int nfb = (N + RB2 - 1) / RB2;         // 128 finK blocks
  finK<<<nfb, THREADS, 0, stream>>>(recSum, recCnt, leader, lslot, C, D, out, N, K, nbm);
}

// Round 12
// 50.900 us; speedup vs baseline: 1.5204x; 1.5204x over previous
//
#include <hip/hip_runtime.h>

#define THREADS 256
#define RB      16     // rows per mainK block
#define RB2     32     // rows per finalize block
#define LCAP    128    // candidate-list capacity
#define KF      80     // compiled K (harness K=80)
#define K2      160    // 2*KF (C|D)
#define NPART   8      // partitioned partials (b&7 ~ XCD id)

typedef float f4 __attribute__((ext_vector_type(4)));

__device__ __forceinline__ unsigned fmap(float x) {   // order-preserving float->uint
  unsigned u = __float_as_uint(x);
  return (u >> 31) ? ~u : (u | 0x80000000u);
}

// ================= mainK: list build + assign + scatter + flush (r5-proven, verbatim) =================
__global__ __launch_bounds__(THREADS)
void mainK(const float* __restrict__ S, const float* __restrict__ J,
           const float* __restrict__ C, const float* __restrict__ D,
           float tau,
           float* __restrict__ slotPart, int* __restrict__ slotCount,
           int* __restrict__ leader, int* __restrict__ lslot,
           int N, int K) {
  __shared__ int   listIdx[LCAP];
  __shared__ float listVal[LCAP];
  __shared__ int   cnts[THREADS];
  __shared__ unsigned long long rowKey[RB];
  __shared__ int   rowSlot[RB];
  __shared__ int   rowLocal[RB];
  __shared__ int   touchSlot[RB];
  __shared__ int   touchCnt[RB];
  __shared__ int   unresR[RB];
  __shared__ int   sT, sNT, sNU;
  __shared__ unsigned long long bkey;
  __shared__ float slab[RB * K2];          // 10.2 KB

  const int tid = threadIdx.x;
  const int b   = blockIdx.x;
  const int i0  = b * RB;

  // ---- A: block-invariant candidate list {j : S[j] >= tau}, index-ascending ----
  int T;
  {
    const bool vec4 = ((N & 3) == 0);
    int cl = 0;
    if (vec4) {
      const int n4 = N >> 2;
      const int per4 = (n4 + THREADS - 1) / THREADS;
      const int a0 = tid * per4, a1 = min(n4, a0 + per4);
      for (int a = a0; a < a1; ++a) {
        f4 v = ((const f4*)S)[a];
        cl += (v.x >= tau) + (v.y >= tau) + (v.z >= tau) + (v.w >= tau);
      }
    } else {
      const int per = (N + THREADS - 1) / THREADS;
      const int j0 = tid * per, j1 = min(N, j0 + per);
      for (int j = j0; j < j1; ++j) cl += (S[j] >= tau);
    }
    cnts[tid] = cl;
    if (tid == 0) { sNU = 0; sNT = 0; }
    __syncthreads();
    if (tid < 64) {                        // wave-0 exclusive prefix over 256 counts
      const int base = tid * 4;
      int a0 = cnts[base], a1 = cnts[base+1], a2 = cnts[base+2], a3 = cnts[base+3];
      int s = a0 + a1 + a2 + a3;
      int inc = s;
      for (int off = 1; off < 64; off <<= 1) { int o = __shfl_up(inc, off, 64); if (tid >= off) inc += o; }
      int exc = inc - s;
      cnts[base] = exc; cnts[base+1] = exc + a0;
      cnts[base+2] = exc + a0 + a1; cnts[base+3] = exc + a0 + a1 + a2;
      if (tid == 63) sT = inc;
    }
    __syncthreads();
    T = sT;
    if (T <= LCAP) {
      int pos = cnts[tid];
      if (vec4) {
        const int n4 = N >> 2;
        const int per4 = (n4 + THREADS - 1) / THREADS;
        const int a0 = tid * per4, a1 = min(n4, a0 + per4);
        for (int a = a0; a < a1; ++a) {
          f4 v = ((const f4*)S)[a];
          if (v.x >= tau) { listIdx[pos] = a*4+0; listVal[pos] = v.x; ++pos; }
          if (v.y >= tau) { listIdx[pos] = a*4+1; listVal[pos] = v.y; ++pos; }
          if (v.z >= tau) { listIdx[pos] = a*4+2; listVal[pos] = v.z; ++pos; }
          if (v.w >= tau) { listIdx[pos] = a*4+3; listVal[pos] = v.w; ++pos; }
        }
      } else {
        const int per = (N + THREADS - 1) / THREADS;
        const int j0 = tid * per, j1 = min(N, j0 + per);
        for (int j = j0; j < j1; ++j) {
          float v = S[j];
          if (v >= tau) { listIdx[pos] = j; listVal[pos] = v; ++pos; }
        }
      }
    }
  }
  const int ovf = (T > LCAP) | (K != KF);  // unconditional-correctness escape hatch
  if (tid < RB) { rowKey[tid] = 0ull; rowSlot[tid] = -1; rowLocal[tid] = -1; }
  __syncthreads();

  // ---- B: leader assign, 16 threads/row over list slots; exact when a top-set nbr exists ----
  {
    const int r = tid & (RB - 1);
    const int g = tid >> 4;
    const int i = i0 + r;
    if (!ovf && i < N) {
      unsigned long long lk = 0ull;
      for (int t = g; t < T; t += 16) {
        const int cand = listIdx[t];
        float v = J[(size_t)cand * N + i];   // symmetric J: coalesced column read
        if (v > 0.5f || cand == i) {         // self always adjacent (eye)
          unsigned long long key = ((unsigned long long)fmap(listVal[t]) << 32)
                                 | (unsigned)(0xFFFFFFFFu - (unsigned)t);
          if (key > lk) lk = key;            // index-ascending slots: min slot == min index
        }
      }
      if (lk) atomicMax(&rowKey[r], lk);
    }
  }
  __syncthreads();
  if (tid < RB) {
    const int i = i0 + tid;
    if (i < N) {
      unsigned long long k = ovf ? 0ull : rowKey[tid];
      if (k != 0ull) {
        int slot = (int)(0xFFFFFFFFu - (unsigned)(k & 0xFFFFFFFFull));
        rowSlot[tid] = slot;
        leader[i] = listIdx[slot];           // plain store: kernel boundary syncs
        lslot[i]  = slot;
      } else {
        lslot[i] = -1;
        int u = atomicAdd(&sNU, 1);
        unresR[u] = tid;
      }
    }
  }
  __syncthreads();

  // ---- B': exact full-row argmax for unresolved rows (expected: none) ----
  const int nu = sNU;
  for (int u = 0; u < nu; ++u) {
    const int rr = unresR[u]; const int ii = i0 + rr;
    if (tid == 0) bkey = 0ull;
    __syncthreads();
    unsigned long long bk = 0ull;
    for (int j = tid; j < N; j += THREADS) {
      float v = J[(size_t)ii * N + j];
      if (v > 0.5f || j == ii) {
        unsigned long long key = ((unsigned long long)fmap(S[j]) << 32)
                               | (unsigned)(0xFFFFFFFFu - (unsigned)j);
        if (key > bk) bk = key;
      }
    }
    if (bk) atomicMax(&bkey, bk);
    __syncthreads();
    if (tid == 0) leader[ii] = (int)(0xFFFFFFFFu - (unsigned)(bkey & 0xFFFFFFFFull));
    __syncthreads();
  }

  // ---- touch map: wave-parallel dedupe of this block's slots (<=16 distinct) ----
  if (tid < RB) {
    int s = rowSlot[tid];
    int first = tid;
    if (s >= 0) { first = 0; while (rowSlot[first] != s) ++first; }
    unsigned long long m = __ballot(s >= 0 && first == tid);
    if (s >= 0) {
      int loc = (int)__popcll(m & ((1ull << first) - 1ull));
      rowLocal[tid] = loc;
      if (first == tid) {
        int cnt = 0;
        for (int rr = 0; rr < RB; ++rr) cnt += (rowSlot[rr] == s);
        touchSlot[loc] = s; touchCnt[loc] = cnt;
      }
    }
    if (tid == 0) sNT = (int)__popcll(m);
  }
  __syncthreads();
  const int nT = sNT;

  // ---- C: per-ROW slab, plain f4 LDS stores ----
  for (int q = tid; q < RB * 40; q += THREADS) {      // 40 f4 per row (C:20|D:20)
    const int rr = q / 40, f = q - rr * 40;
    const int i = i0 + rr;
    if (i >= N || rowLocal[rr] < 0) continue;
    f4 v;
    if (f < 20) v = *(const f4*)(C + (size_t)i * KF + f * 4);
    else        v = *(const f4*)(D + (size_t)i * KF + (f - 20) * 4);
    *(f4*)&slab[rr * K2 + (f < 20 ? f * 4 : KF + (f - 20) * 4)] = v;
  }
  __syncthreads();

  // ---- D: flush counts + per-slot row-sums into partition b&7 ----
  if (tid < nT) atomicAdd(&slotCount[touchSlot[tid]], touchCnt[tid]);
  {
    const int p = b & (NPART - 1);
    for (int q = tid; q < nT * 40; q += THREADS) {
      const int loc = q / 40, f4i = q - loc * 40;
      float ax = 0.f, ay = 0.f, az = 0.f, aw = 0.f;
      for (int rr = 0; rr < RB; ++rr) {
        if (rowLocal[rr] == loc) {
          const f4 v = *(const f4*)&slab[rr * K2 + f4i * 4];
          ax += v.x; ay += v.y; az += v.z; aw += v.w;
        }
      }
      float* dst = slotPart + ((size_t)p * LCAP + touchSlot[loc]) * K2 + f4i * 4;
      atomicAdd(dst + 0, ax); atomicAdd(dst + 1, ay);
      atomicAdd(dst + 2, az); atomicAdd(dst + 3, aw);
    }
  }
}

// ============ finRowK: row-block finalize with per-block slot cache (one partition-reduce per slot) ============
__global__ __launch_bounds__(THREADS)
void finRowK(const float* __restrict__ slotPart, const int* __restrict__ slotCount,
             const int* __restrict__ leader, const int* __restrict__ lslot,
             const float* __restrict__ C, const float* __restrict__ D,
             float* __restrict__ out, int N, int K) {
  __shared__ float accS[RB2 * K2];   // 20.5 KB (<=32 distinct slots per 32 rows)
  __shared__ int   rslot[RB2];
  __shared__ int   rowLocal[RB2];
  __shared__ int   touchSlot[RB2];
  __shared__ float invS[RB2];
  __shared__ int   sNT;
  const int tid = threadIdx.x;
  const int r0 = blockIdx.x * RB2;
  const size_t NK = (size_t)N * K;

  if (tid < RB2) {
    const int i = r0 + tid;
    rslot[tid] = (i < N) ? lslot[i] : -2;
  }
  __syncthreads();
  if (tid < RB2) {                     // first 32 lanes of wave 0: ballot dedupe
    int s = rslot[tid];
    int first = tid;
    if (s >= 0) { first = 0; while (rslot[first] != s) ++first; }
    unsigned long long m = __ballot(s >= 0 && first == tid);
    if (s >= 0) {
      int loc = (int)__popcll(m & ((1ull << first) - 1ull));
      rowLocal[tid] = loc;
      if (first == tid) touchSlot[loc] = s;
    } else rowLocal[tid] = -1;
    if (tid == 0) sNT = (int)__popcll(m);
  }
  __syncthreads();
  const int nT = sNT;
  if (tid < nT) {
    const int c = slotCount[touchSlot[tid]];
    invS[tid] = 1.0f / (float)(c > 0 ? c : 1);
  }

  // reduce 8 partitions ONCE per touched slot into LDS (vs once per element in r5)
  for (int q = tid; q < nT * 40; q += THREADS) {
    const int loc = q / 40, f = q - loc * 40;
    const f4* base = (const f4*)slotPart + (size_t)touchSlot[loc] * 40 + f;
    f4 a = { 0.f, 0.f, 0.f, 0.f };
    #pragma unroll
    for (int p = 0; p < NPART; ++p)
      a += base[(size_t)p * LCAP * 40];
    *(f4*)&accS[loc * K2 + f * 4] = a;
  }
  __syncthreads();

  // write own rows (coalesced f4)
  for (int q = tid; q < RB2 * 40; q += THREADS) {
    const int rr = q / 40, f = q - rr * 40;
    const int i = r0 + rr;
    if (i >= N) continue;
    const int loc = rowLocal[rr];
    if (loc < 0) continue;
    const float iv = invS[loc];
    const f4 v0 = *(const f4*)&accS[loc * K2 + (f < 20 ? f * 4 : KF + (f - 20) * 4)];
    f4 v = { v0.x * iv, v0.y * iv, v0.z * iv, v0.w * iv };
    const size_t off = (f < 20) ? ((size_t)i * KF + f * 4)
                                : (NK + (size_t)i * KF + (f - 20) * 4);
    *(f4*)(out + off) = v;
  }

  // fallback rows: exact leader-scan mean (expected: none; any K)
  for (int rr = 0; rr < RB2; ++rr) {
    if (rslot[rr] != -1) continue;
    const int ii = r0 + rr;
    const int m = leader[ii];
    for (int k = tid; k < K; k += THREADS) {
      float sc = 0.f, sd = 0.f; int cc = 0;
      for (int y = 0; y < N; ++y)
        if (leader[y] == m) { sc += C[(size_t)y * K + k]; sd += D[(size_t)y * K + k]; ++cc; }
      const float iv = 1.0f / (float)(cc > 0 ? cc : 1);
      out[(size_t)ii * K + k] = sc * iv;
      out[NK + (size_t)ii * K + k] = sd * iv;
    }
  }
}

extern "C" void kernel_launch(void* const* d_in, const int* in_sizes, int n_in,
                              void* d_out, int out_size, void* d_ws, size_t ws_size,
                              hipStream_t stream) {
  (void)n_in; (void)out_size; (void)ws_size;
  const float* S = (const float*)d_in[0];
  const float* J = (const float*)d_in[1];
  const float* C = (const float*)d_in[2];
  const float* D = (const float*)d_in[3];
  float* out = (float*)d_out;
  const int N = in_sizes[0];
  const int K = in_sizes[2] / N;

  // ws layout (zeroed prefix): slotPart[NPART][LCAP][K2] | slotCount[LCAP] || leader[N] | lslot[N]
  float* slotPart  = (float*)d_ws;
  int*   slotCount = (int*)(slotPart + (size_t)NPART * LCAP * K2);
  int*   leader    = slotCount + LCAP;
  int*   lslot     = leader + N;

  const size_t zbytes = ((size_t)NPART * LCAP * K2 + LCAP) * sizeof(float);   // ~656 KB
  (void)hipMemsetAsync(d_ws, 0, zbytes, stream);

  const float tau = 1.0f - 48.0f / (float)N;   // targets E[T]=48; any tau is correct
  const int nblk = (N + RB - 1) / RB;          // 512 blocks for N=8192
  mainK<<<nblk, THREADS, 0, stream>>>(S, J, C, D, tau, slotPart, slotCount,
                                      leader, lslot, N, K);
  const int nfb = (N + RB2 - 1) / RB2;         // 256 blocks
  finRowK<<<nfb, THREADS, 0, stream>>>(slotPart, slotCount, leader, lslot,
                                       C, D, out, N, K);
}

// Round 13
// 47.234 us; speedup vs baseline: 1.6384x; 1.0776x over previous
//
#include <hip/hip_runtime.h>

#define THREADS 256
#define RB      16     // rows per mainK block
#define LCAP    128    // candidate-list capacity
#define KF      80     // compiled K (harness K=80)
#define K2      160    // 2*KF (C|D)
#define NPART   8      // partitioned partials (b&7 ~ XCD id)

typedef float f4 __attribute__((ext_vector_type(4)));

__device__ __forceinline__ unsigned fmap(float x) {   // order-preserving float->uint
  unsigned u = __float_as_uint(x);
  return (u >> 31) ? ~u : (u | 0x80000000u);
}

// ================= mainK: list build + assign + scatter + flush (r5 + shfl dedupe) =================
__global__ __launch_bounds__(THREADS)
void mainK(const float* __restrict__ S, const float* __restrict__ J,
           const float* __restrict__ C, const float* __restrict__ D,
           float tau,
           float* __restrict__ slotPart, int* __restrict__ slotCount,
           int* __restrict__ leader, int* __restrict__ lslot,
           int N, int K) {
  __shared__ int   listIdx[LCAP];
  __shared__ float listVal[LCAP];
  __shared__ int   cnts[THREADS];
  __shared__ unsigned long long rowKey[RB];
  __shared__ int   rowSlot[RB];
  __shared__ int   rowLocal[RB];
  __shared__ int   touchSlot[RB];
  __shared__ int   touchCnt[RB];
  __shared__ int   unresR[RB];
  __shared__ int   sT, sNT, sNU;
  __shared__ unsigned long long bkey;
  __shared__ float slab[RB * K2];          // 10.2 KB

  const int tid = threadIdx.x;
  const int b   = blockIdx.x;
  const int i0  = b * RB;

  // ---- A: block-invariant candidate list {j : S[j] >= tau}, index-ascending ----
  int T;
  {
    const bool vec4 = ((N & 3) == 0);
    int cl = 0;
    if (vec4) {
      const int n4 = N >> 2;
      const int per4 = (n4 + THREADS - 1) / THREADS;
      const int a0 = tid * per4, a1 = min(n4, a0 + per4);
      for (int a = a0; a < a1; ++a) {
        f4 v = ((const f4*)S)[a];
        cl += (v.x >= tau) + (v.y >= tau) + (v.z >= tau) + (v.w >= tau);
      }
    } else {
      const int per = (N + THREADS - 1) / THREADS;
      const int j0 = tid * per, j1 = min(N, j0 + per);
      for (int j = j0; j < j1; ++j) cl += (S[j] >= tau);
    }
    cnts[tid] = cl;
    if (tid == 0) { sNU = 0; sNT = 0; }
    __syncthreads();
    if (tid < 64) {                        // wave-0 exclusive prefix over 256 counts
      const int base = tid * 4;
      int a0 = cnts[base], a1 = cnts[base+1], a2 = cnts[base+2], a3 = cnts[base+3];
      int s = a0 + a1 + a2 + a3;
      int inc = s;
      for (int off = 1; off < 64; off <<= 1) { int o = __shfl_up(inc, off, 64); if (tid >= off) inc += o; }
      int exc = inc - s;
      cnts[base] = exc; cnts[base+1] = exc + a0;
      cnts[base+2] = exc + a0 + a1; cnts[base+3] = exc + a0 + a1 + a2;
      if (tid == 63) sT = inc;
    }
    __syncthreads();
    T = sT;
    if (T <= LCAP) {
      int pos = cnts[tid];
      if (vec4) {
        const int n4 = N >> 2;
        const int per4 = (n4 + THREADS - 1) / THREADS;
        const int a0 = tid * per4, a1 = min(n4, a0 + per4);
        for (int a = a0; a < a1; ++a) {
          f4 v = ((const f4*)S)[a];
          if (v.x >= tau) { listIdx[pos] = a*4+0; listVal[pos] = v.x; ++pos; }
          if (v.y >= tau) { listIdx[pos] = a*4+1; listVal[pos] = v.y; ++pos; }
          if (v.z >= tau) { listIdx[pos] = a*4+2; listVal[pos] = v.z; ++pos; }
          if (v.w >= tau) { listIdx[pos] = a*4+3; listVal[pos] = v.w; ++pos; }
        }
      } else {
        const int per = (N + THREADS - 1) / THREADS;
        const int j0 = tid * per, j1 = min(N, j0 + per);
        for (int j = j0; j < j1; ++j) {
          float v = S[j];
          if (v >= tau) { listIdx[pos] = j; listVal[pos] = v; ++pos; }
        }
      }
    }
  }
  const int ovf = (T > LCAP) | (K != KF);  // unconditional-correctness escape hatch
  if (tid < RB) { rowKey[tid] = 0ull; rowSlot[tid] = -1; rowLocal[tid] = -1; }
  __syncthreads();

  // ---- B: leader assign, 16 threads/row over list slots; exact when a top-set nbr exists ----
  {
    const int r = tid & (RB - 1);
    const int g = tid >> 4;
    const int i = i0 + r;
    if (!ovf && i < N) {
      unsigned long long lk = 0ull;
      for (int t = g; t < T; t += 16) {
        const int cand = listIdx[t];
        float v = J[(size_t)cand * N + i];   // symmetric J: coalesced column read
        if (v > 0.5f || cand == i) {         // self always adjacent (eye)
          unsigned long long key = ((unsigned long long)fmap(listVal[t]) << 32)
                                 | (unsigned)(0xFFFFFFFFu - (unsigned)t);
          if (key > lk) lk = key;            // index-ascending slots: min slot == min index
        }
      }
      if (lk) atomicMax(&rowKey[r], lk);
    }
  }
  __syncthreads();
  if (tid < RB) {
    const int i = i0 + tid;
    if (i < N) {
      unsigned long long k = ovf ? 0ull : rowKey[tid];
      if (k != 0ull) {
        int slot = (int)(0xFFFFFFFFu - (unsigned)(k & 0xFFFFFFFFull));
        rowSlot[tid] = slot;
        leader[i] = listIdx[slot];           // plain store: kernel boundary syncs
        lslot[i]  = slot;
      } else {
        lslot[i] = -1;
        int u = atomicAdd(&sNU, 1);
        unresR[u] = tid;
      }
    }
  }
  __syncthreads();

  // ---- B': exact full-row argmax for unresolved rows (expected: none) ----
  const int nu = sNU;
  for (int u = 0; u < nu; ++u) {
    const int rr = unresR[u]; const int ii = i0 + rr;
    if (tid == 0) bkey = 0ull;
    __syncthreads();
    unsigned long long bk = 0ull;
    for (int j = tid; j < N; j += THREADS) {
      float v = J[(size_t)ii * N + j];
      if (v > 0.5f || j == ii) {
        unsigned long long key = ((unsigned long long)fmap(S[j]) << 32)
                               | (unsigned)(0xFFFFFFFFu - (unsigned)j);
        if (key > bk) bk = key;
      }
    }
    if (bk) atomicMax(&bkey, bk);
    __syncthreads();
    if (tid == 0) leader[ii] = (int)(0xFFFFFFFFu - (unsigned)(bkey & 0xFFFFFFFFull));
    __syncthreads();
  }

  // ---- touch map: shfl-based dedupe (no serial LDS chain, no count loop) ----
  if (tid < RB) {                          // lanes 0..15 of wave 0
    const int s = rowSlot[tid];
    unsigned match = 0;
    #pragma unroll
    for (int k = 0; k < RB; ++k)
      match |= ((__shfl(s, k, 64) == s) ? 1u : 0u) << k;   // uniform source: no divergence
    const int first = __ffs(match) - 1;
    unsigned long long m = __ballot(s >= 0 && first == tid);
    if (s >= 0) {
      const int loc = (int)__popcll(m & ((1ull << first) - 1ull));
      rowLocal[tid] = loc;
      if (first == tid) { touchSlot[loc] = s; touchCnt[loc] = __popc(match); }
    }
    if (tid == 0) sNT = (int)__popcll(m);
  }
  __syncthreads();
  const int nT = sNT;

  // ---- C: per-ROW slab, plain f4 LDS stores ----
  for (int q = tid; q < RB * 40; q += THREADS) {      // 40 f4 per row (C:20|D:20)
    const int rr = q / 40, f = q - rr * 40;
    const int i = i0 + rr;
    if (i >= N || rowLocal[rr] < 0) continue;
    f4 v;
    if (f < 20) v = *(const f4*)(C + (size_t)i * KF + f * 4);
    else        v = *(const f4*)(D + (size_t)i * KF + (f - 20) * 4);
    *(f4*)&slab[rr * K2 + (f < 20 ? f * 4 : KF + (f - 20) * 4)] = v;
  }
  __syncthreads();

  // ---- D: flush counts + per-slot row-sums into partition b&7 ----
  if (tid < nT) atomicAdd(&slotCount[touchSlot[tid]], touchCnt[tid]);
  {
    const int p = b & (NPART - 1);
    for (int q = tid; q < nT * 40; q += THREADS) {
      const int loc = q / 40, f4i = q - loc * 40;
      float ax = 0.f, ay = 0.f, az = 0.f, aw = 0.f;
      for (int rr = 0; rr < RB; ++rr) {
        if (rowLocal[rr] == loc) {
          const f4 v = *(const f4*)&slab[rr * K2 + f4i * 4];
          ax += v.x; ay += v.y; az += v.z; aw += v.w;
        }
      }
      float* dst = slotPart + ((size_t)p * LCAP + touchSlot[loc]) * K2 + f4i * 4;
      atomicAdd(dst + 0, ax); atomicAdd(dst + 1, ay);
      atomicAdd(dst + 2, az); atomicAdd(dst + 3, aw);
    }
  }
}

// ========= finalizeK: merged C/D — one thread writes both halves of (i,k0) (element-centric) =========
__global__ __launch_bounds__(THREADS)
void finalizeK(const float* __restrict__ slotPart, const int* __restrict__ slotCount,
               const int* __restrict__ leader, const int* __restrict__ lslot,
               const float* __restrict__ C, const float* __restrict__ D,
               float* __restrict__ out, int N, int K) {
  const int NK4 = N * K / 4;
  const size_t NKc = (size_t)N * K;
  int idx = blockIdx.x * THREADS + threadIdx.x;
  if (idx >= NK4) return;
  const int kq = K / 4;
  const int i  = idx / kq;
  const int k0 = (idx - i * kq) * 4;
  const int slot = lslot[i];
  f4 accC, accD;
  if (slot >= 0) {
    const float* baseC = slotPart + (size_t)slot * K2 + k0;
    f4 aC = { 0.f, 0.f, 0.f, 0.f }, aD = { 0.f, 0.f, 0.f, 0.f };
    #pragma unroll
    for (int p = 0; p < NPART; ++p) {
      const float* bp = baseC + (size_t)p * LCAP * K2;
      aC += *(const f4*)bp;
      aD += *(const f4*)(bp + KF);
    }
    const int c = slotCount[slot];
    const float inv = 1.0f / (float)(c > 0 ? c : 1);
    accC = aC * inv; accD = aD * inv;
  } else {
    // exact leader-scan mean (expected never; correctness escape hatch)
    const int m = leader[i];
    f4 sC = { 0.f, 0.f, 0.f, 0.f }, sD = { 0.f, 0.f, 0.f, 0.f };
    int cc = 0;
    for (int y = 0; y < N; ++y) {
      if (leader[y] == m) {
        sC += *(const f4*)(C + (size_t)y * K + k0);
        sD += *(const f4*)(D + (size_t)y * K + k0);
        ++cc;
      }
    }
    const float inv = 1.0f / (float)(cc > 0 ? cc : 1);
    accC = sC * inv; accD = sD * inv;
  }
  *(f4*)(out + (size_t)i * K + k0)       = accC;
  *(f4*)(out + NKc + (size_t)i * K + k0) = accD;
}

// ================= scalar finalize for K % 4 != 0 (rare shape; correctness path) =================
__global__ __launch_bounds__(THREADS)
void finalizeScalarK(const int* __restrict__ leader,
                     const float* __restrict__ C, const float* __restrict__ D,
                     float* __restrict__ out, int N, int K) {
  const int NK = N * K;
  int idx = blockIdx.x * THREADS + threadIdx.x;
  if (idx >= 2 * NK) return;
  const bool isD = (idx >= NK);
  const int rem = isD ? idx - NK : idx;
  const int i = rem / K, k = rem - i * K;
  const int m = leader[i];
  const float* src = isD ? D : C;
  float s = 0.f; int cc = 0;
  for (int y = 0; y < N; ++y)
    if (leader[y] == m) { s += src[(size_t)y * K + k]; ++cc; }
  out[idx] = s / (float)(cc > 0 ? cc : 1);
}

extern "C" void kernel_launch(void* const* d_in, const int* in_sizes, int n_in,
                              void* d_out, int out_size, void* d_ws, size_t ws_size,
                              hipStream_t stream) {
  (void)n_in; (void)out_size; (void)ws_size;
  const float* S = (const float*)d_in[0];
  const float* J = (const float*)d_in[1];
  const float* C = (const float*)d_in[2];
  const float* D = (const float*)d_in[3];
  float* out = (float*)d_out;
  const int N = in_sizes[0];
  const int K = in_sizes[2] / N;
  const int NK = N * K;

  // ws layout (zeroed prefix): slotPart[NPART][LCAP][K2] | slotCount[LCAP] || leader[N] | lslot[N]
  float* slotPart  = (float*)d_ws;
  int*   slotCount = (int*)(slotPart + (size_t)NPART * LCAP * K2);
  int*   leader    = slotCount + LCAP;
  int*   lslot     = leader + N;

  const size_t zbytes = ((size_t)NPART * LCAP * K2 + LCAP) * sizeof(float);   // ~656 KB
  (void)hipMemsetAsync(d_ws, 0, zbytes, stream);

  const float tau = 1.0f - 48.0f / (float)N;   // targets E[T]=48; any tau is correct
  const int nblk = (N + RB - 1) / RB;          // 512 blocks for N=8192
  mainK<<<nblk, THREADS, 0, stream>>>(S, J, C, D, tau, slotPart, slotCount,
                                      leader, lslot, N, K);
  if ((K & 3) == 0) {
    finalizeK<<<((NK / 4) + THREADS - 1) / THREADS, THREADS, 0, stream>>>(
        slotPart, slotCount, leader, lslot, C, D, out, N, K);
  } else {
    finalizeScalarK<<<(2 * NK + THREADS - 1) / THREADS, THREADS, 0, stream>>>(
        leader, C, D, out, N, K);
  }
}